// Round 1
// baseline (1063.082 us; speedup 1.0000x reference)
//
#include <hip/hip_runtime.h>

#define B_   128
#define T_   256
#define C_   384
#define H_   6
#define D_   64
#define M_   128
#define WIN_ 64
#define TT_  384   // T + M
#define C3_  1152  // 3*C

typedef unsigned int  uint;
typedef unsigned short ushort;

__device__ __forceinline__ float lo16(uint u){ union{uint i;float f;}c; c.i = u << 16;         return c.f; }
__device__ __forceinline__ float hi16(uint u){ union{uint i;float f;}c; c.i = u & 0xffff0000u; return c.f; }
__device__ __forceinline__ ushort f2bf(float f){
  union{float f;uint u;}c; c.f = f;
  uint x = c.u;
  return (ushort)((x + 0x7fffu + ((x >> 16) & 1u)) >> 16);  // RNE
}

// ---------------------------------------------------------------------------
// Kernel 1: qkv = x @ W_qkv + b_qkv   [32768,384] @ [384,1152] -> bf16 ws
// 64x64 tile, BK=32, 256 threads, 4x4 per thread, f32 vector FMA.
// ---------------------------------------------------------------------------
__global__ __launch_bounds__(256)
void k_qkv_gemm(const float* __restrict__ x, const float* __restrict__ W,
                const float* __restrict__ bias, ushort* __restrict__ qkv)
{
  __shared__ float As[32][68];   // [k][m], pad 68 keeps float4 16B alignment
  __shared__ float Bs[32][68];   // [k][n]
  const int bm = blockIdx.x * 64;
  const int bn = blockIdx.y * 64;
  const int tid = threadIdx.x;
  const int tx = tid & 15, ty = tid >> 4;
  float acc[4][4] = {};
  for (int k0 = 0; k0 < C_; k0 += 32) {
    #pragma unroll
    for (int i = 0; i < 8; ++i) {
      int idx = i * 256 + tid;
      int m  = idx >> 5, kk = idx & 31;
      As[kk][m] = x[(size_t)(bm + m) * C_ + k0 + kk];
      int kb = idx >> 6, nn = idx & 63;
      Bs[kb][nn] = W[(size_t)(k0 + kb) * C3_ + bn + nn];
    }
    __syncthreads();
    #pragma unroll
    for (int kk = 0; kk < 32; ++kk) {
      float4 a = *(const float4*)&As[kk][ty * 4];
      float4 b = *(const float4*)&Bs[kk][tx * 4];
      float av[4] = {a.x, a.y, a.z, a.w};
      float bv[4] = {b.x, b.y, b.z, b.w};
      #pragma unroll
      for (int ii = 0; ii < 4; ++ii)
        #pragma unroll
        for (int jj = 0; jj < 4; ++jj)
          acc[ii][jj] += av[ii] * bv[jj];
    }
    __syncthreads();
  }
  #pragma unroll
  for (int ii = 0; ii < 4; ++ii) {
    int row = bm + ty * 4 + ii;
    int col = bn + tx * 4;
    uint u0 = (uint)f2bf(acc[ii][0] + bias[col + 0]) | ((uint)f2bf(acc[ii][1] + bias[col + 1]) << 16);
    uint u1 = (uint)f2bf(acc[ii][2] + bias[col + 2]) | ((uint)f2bf(acc[ii][3] + bias[col + 3]) << 16);
    uint2 uu; uu.x = u0; uu.y = u1;
    *(uint2*)&qkv[(size_t)row * C3_ + col] = uu;
  }
}

// ---------------------------------------------------------------------------
// Kernel 2: attention. One block per (b,h); 256 threads = 1 thread per query.
// K/V staged in LDS (bf16, row pad 68 -> 136B rows, 8B aligned).
// Memory prefix rows 0..127 from `memory` (unprojected), self rows from qkv.
// Logits are tiny (|s| < ~3) -> plain exp(s), no max subtraction, no rescale.
// Gate is folded into the y store.
// ---------------------------------------------------------------------------
__global__ __launch_bounds__(256, 1)
void k_attn(const ushort* __restrict__ qkv, const float* __restrict__ memory,
            const float* __restrict__ gate, ushort* __restrict__ y)
{
  constexpr int LDK = 68;
  __shared__ ushort Ks[TT_][LDK];
  __shared__ ushort Vs[TT_][LDK];
  const int b = blockIdx.x, h = blockIdx.y;
  const int tid = threadIdx.x;

  // stage memory rows (K == V == memory slice for this head)
  for (int i = tid; i < M_ * 32; i += 256) {
    int r = i >> 5, d2 = i & 31;
    float f0 = memory[r * C_ + h * 64 + 2 * d2];
    float f1 = memory[r * C_ + h * 64 + 2 * d2 + 1];
    uint u = (uint)f2bf(f0) | ((uint)f2bf(f1) << 16);
    *(uint*)&Ks[r][2 * d2] = u;
    *(uint*)&Vs[r][2 * d2] = u;
  }
  // stage self K/V rows from qkv ws (already bf16 -> raw uint copies)
  for (int i = tid; i < T_ * 32; i += 256) {
    int t = i >> 5, d2 = i & 31;
    size_t base = ((size_t)(b * T_ + t)) * C3_ + h * 64 + 2 * d2;
    *(uint*)&Ks[M_ + t][2 * d2] = *(const uint*)(qkv + base + C_);
    *(uint*)&Vs[M_ + t][2 * d2] = *(const uint*)(qkv + base + 2 * C_);
  }

  // q for this thread's query, pre-scaled by 1/sqrt(D)
  float q[64];
  {
    size_t base = ((size_t)(b * T_ + tid)) * C3_ + h * 64;
    #pragma unroll
    for (int d2 = 0; d2 < 32; ++d2) {
      uint u = *(const uint*)(qkv + base + 2 * d2);
      q[2 * d2]     = lo16(u) * 0.125f;
      q[2 * d2 + 1] = hi16(u) * 0.125f;
    }
  }
  __syncthreads();

  float acc[64];
  #pragma unroll
  for (int d = 0; d < 64; ++d) acc[d] = 0.f;
  float l = 0.f;

  auto key = [&](int r) {
    const uint2* kr = (const uint2*)&Ks[r][0];
    float s0 = 0, s1 = 0, s2 = 0, s3 = 0;
    #pragma unroll
    for (int c = 0; c < 16; ++c) {
      uint2 u = kr[c];
      s0 += lo16(u.x) * q[4 * c];
      s1 += hi16(u.x) * q[4 * c + 1];
      s2 += lo16(u.y) * q[4 * c + 2];
      s3 += hi16(u.y) * q[4 * c + 3];
    }
    float p = __expf((s0 + s1) + (s2 + s3));
    l += p;
    const uint2* vr = (const uint2*)&Vs[r][0];
    #pragma unroll
    for (int c = 0; c < 16; ++c) {
      uint2 u = vr[c];
      acc[4 * c]     += p * lo16(u.x);
      acc[4 * c + 1] += p * hi16(u.x);
      acc[4 * c + 2] += p * lo16(u.y);
      acc[4 * c + 3] += p * hi16(u.y);
    }
  };

  const int i = tid;                       // query index
  for (int j = 0; j < M_; ++j) key(j);     // memory prefix: always visible
  const int j0 = (i >= WIN_) ? (i - WIN_) : 0;
  for (int j = j0; j <= i; ++j) key(M_ + j);  // causal local window

  const float inv = 1.0f / l;
  size_t ybase = ((size_t)(b * T_ + i)) * C_ + h * 64;
  #pragma unroll
  for (int d2 = 0; d2 < 32; ++d2) {
    float v0 = acc[2 * d2]     * inv * gate[h * 64 + 2 * d2];
    float v1 = acc[2 * d2 + 1] * inv * gate[h * 64 + 2 * d2 + 1];
    uint u = (uint)f2bf(v0) | ((uint)f2bf(v1) << 16);
    *(uint*)&y[ybase + 2 * d2] = u;
  }
}

// ---------------------------------------------------------------------------
// Kernel 3: out = y_gated @ W_proj + b_proj   [32768,384] @ [384,384] -> f32
// (gate already applied in k_attn)
// ---------------------------------------------------------------------------
__global__ __launch_bounds__(256)
void k_proj_gemm(const ushort* __restrict__ y, const float* __restrict__ W,
                 const float* __restrict__ bias, float* __restrict__ out)
{
  __shared__ float As[32][68];
  __shared__ float Bs[32][68];
  const int bm = blockIdx.x * 64;
  const int bn = blockIdx.y * 64;
  const int tid = threadIdx.x;
  const int tx = tid & 15, ty = tid >> 4;
  float acc[4][4] = {};
  for (int k0 = 0; k0 < C_; k0 += 32) {
    #pragma unroll
    for (int i = 0; i < 4; ++i) {            // A: 64 rows x 16 bf16-pairs
      int idx = i * 256 + tid;
      int m = idx >> 4, d2 = idx & 15;
      uint u = *(const uint*)(y + (size_t)(bm + m) * C_ + k0 + 2 * d2);
      As[2 * d2][m]     = lo16(u);
      As[2 * d2 + 1][m] = hi16(u);
    }
    #pragma unroll
    for (int i = 0; i < 8; ++i) {
      int idx = i * 256 + tid;
      int kb = idx >> 6, nn = idx & 63;
      Bs[kb][nn] = W[(size_t)(k0 + kb) * C_ + bn + nn];
    }
    __syncthreads();
    #pragma unroll
    for (int kk = 0; kk < 32; ++kk) {
      float4 a = *(const float4*)&As[kk][ty * 4];
      float4 b = *(const float4*)&Bs[kk][tx * 4];
      float av[4] = {a.x, a.y, a.z, a.w};
      float bv[4] = {b.x, b.y, b.z, b.w};
      #pragma unroll
      for (int ii = 0; ii < 4; ++ii)
        #pragma unroll
        for (int jj = 0; jj < 4; ++jj)
          acc[ii][jj] += av[ii] * bv[jj];
    }
    __syncthreads();
  }
  #pragma unroll
  for (int ii = 0; ii < 4; ++ii) {
    int row = bm + ty * 4 + ii;
    int col = bn + tx * 4;
    float4 o;
    o.x = acc[ii][0] + bias[col + 0];
    o.y = acc[ii][1] + bias[col + 1];
    o.z = acc[ii][2] + bias[col + 2];
    o.w = acc[ii][3] + bias[col + 3];
    *(float4*)&out[(size_t)row * C_ + col] = o;
  }
}

extern "C" void kernel_launch(void* const* d_in, const int* in_sizes, int n_in,
                              void* d_out, int out_size, void* d_ws, size_t ws_size,
                              hipStream_t stream) {
  const float* x      = (const float*)d_in[0];
  const float* memory = (const float*)d_in[1];
  const float* W_qkv  = (const float*)d_in[2];
  const float* b_qkv  = (const float*)d_in[3];
  const float* W_proj = (const float*)d_in[4];
  const float* b_proj = (const float*)d_in[5];
  const float* gate   = (const float*)d_in[6];
  float* out = (float*)d_out;

  ushort* qkv_ws = (ushort*)d_ws;                          // [B,T,3C] bf16 (75.5 MB)
  ushort* y_ws   = qkv_ws + (size_t)B_ * T_ * C3_;         // [B,T,C]  bf16, gate folded (25 MB)

  dim3 blk(256);
  dim3 g1(T_ * B_ / 64, C3_ / 64);   // (512, 18)
  k_qkv_gemm<<<g1, blk, 0, stream>>>(x, W_qkv, b_qkv, qkv_ws);

  dim3 g2(B_, H_);                   // (128, 6)
  k_attn<<<g2, blk, 0, stream>>>(qkv_ws, memory, gate, y_ws);

  dim3 g3(T_ * B_ / 64, C_ / 64);    // (512, 6)
  k_proj_gemm<<<g3, blk, 0, stream>>>(y_ws, W_proj, b_proj, out);
}

// Round 2
// 163.758 us; speedup vs baseline: 6.4918x; 6.4918x over previous
//
#include <hip/hip_runtime.h>

#define B_   128
#define T_   256
#define C_   384
#define H_   6
#define D_   64
#define M_   128
#define WIN_ 64
#define TT_  384   // T + M
#define C3_  1152  // 3*C

typedef unsigned int   uint;
typedef unsigned short ushort;
typedef __attribute__((ext_vector_type(8))) short bf16x8;   // 8 bf16 (4 VGPR)
typedef __attribute__((ext_vector_type(4))) float f32x4;    // 4 f32 (C/D frag)

#define AS1 __attribute__((address_space(1)))
#define AS3 __attribute__((address_space(3)))

#define MFMA16(a, b, c) __builtin_amdgcn_mfma_f32_16x16x32_bf16((a), (b), (c), 0, 0, 0)

__device__ __forceinline__ ushort f2bf(float f) {
  union { float f; uint u; } c; c.f = f;
  uint x = c.u;
  return (ushort)((x + 0x7fffu + ((x >> 16) & 1u)) >> 16);  // RNE
}

__device__ __forceinline__ void gload_lds16(const ushort* g, ushort* l) {
  __builtin_amdgcn_global_load_lds((const AS1 uint*)g, (AS3 uint*)l, 16, 0, 0);
}

// ---------------------------------------------------------------------------
// Prep: x -> bf16, memory -> bf16, W_qkv -> bf16 transposed [N][K],
// W_proj -> bf16 transposed [N][K]. One grid-stride kernel, segmented by id.
// ---------------------------------------------------------------------------
#define NX4_  ((B_ * T_ * C_) / 4)   // 3145728
#define NM4_  ((M_ * C_) / 4)        // 12288
#define NWQ_  (C_ * C3_)             // 442368
#define NWP_  (C_ * C_)              // 147456

__global__ __launch_bounds__(256)
void k_prep(const float* __restrict__ x, const float* __restrict__ memory,
            const float* __restrict__ Wq, const float* __restrict__ Wp,
            ushort* __restrict__ x_bf, ushort* __restrict__ mem_bf,
            ushort* __restrict__ Wq_t, ushort* __restrict__ Wp_t)
{
  int id = blockIdx.x * 256 + threadIdx.x;
  if (id < NX4_) {
    float4 f = ((const float4*)x)[id];
    ushort4 u; u.x = f2bf(f.x); u.y = f2bf(f.y); u.z = f2bf(f.z); u.w = f2bf(f.w);
    *(ushort4*)&x_bf[id * 4] = u;
    return;
  }
  id -= NX4_;
  if (id < NM4_) {
    float4 f = ((const float4*)memory)[id];
    ushort4 u; u.x = f2bf(f.x); u.y = f2bf(f.y); u.z = f2bf(f.z); u.w = f2bf(f.w);
    *(ushort4*)&mem_bf[id * 4] = u;
    return;
  }
  id -= NM4_;
  if (id < NWQ_) {                       // Wq_t[n*384 + k] = Wq[k*1152 + n]
    int n = id / C_, k = id % C_;
    Wq_t[id] = f2bf(Wq[(size_t)k * C3_ + n]);
    return;
  }
  id -= NWQ_;
  if (id < NWP_) {                       // Wp_t[n*384 + k] = Wp[k*384 + n]
    int n = id / C_, k = id % C_;
    Wp_t[id] = f2bf(Wp[(size_t)k * C_ + n]);
  }
}

// ---------------------------------------------------------------------------
// MFMA GEMM: C[M][N] = A[M][384] * Bt[N][384]^T + bias.  128x128 tile, BK=32,
// 4 waves (each a 64x64 quadrant), double-buffered global_load_lds with
// counted vmcnt. LDS tiles XOR-swizzled via pre-swizzled SOURCE (linear dest).
// ---------------------------------------------------------------------------
template<int N, bool OUT_F32>
__global__ __launch_bounds__(256, 2)
void k_gemm(const ushort* __restrict__ A, const ushort* __restrict__ Bt,
            const float* __restrict__ bias, void* __restrict__ Cout)
{
  __shared__ ushort As[2][128 * 32];
  __shared__ ushort Bs[2][128 * 32];
  const int bm = blockIdx.x * 128;
  const int bn = blockIdx.y * 128;
  const int tid = threadIdx.x;
  const int lane = tid & 63, w = tid >> 6;
  const int wr = w >> 1, wc = w & 1;
  const int g = lane >> 4, l15 = lane & 15;

  f32x4 acc[4][4] = {};

  // stage one K-step (k0) into buffer buf: 512 16B slots each for A and B
  auto stage = [&](int buf, int k0) {
    #pragma unroll
    for (int i = 0; i < 2; ++i) {
      int s = i * 256 + tid;
      int row = s >> 2, cS = s & 3;
      int c = cS ^ ((row >> 1) & 3);          // inverse swizzle on source
      gload_lds16(A  + (size_t)(bm + row) * C_ + k0 + c * 8, &As[buf][s * 8]);
      gload_lds16(Bt + (size_t)(bn + row) * C_ + k0 + c * 8, &Bs[buf][s * 8]);
    }
  };

  stage(0, 0);
  for (int t = 0; t < 12; ++t) {
    int cur = t & 1;
    if (t < 11) {
      stage(cur ^ 1, (t + 1) * 32);
      asm volatile("s_waitcnt vmcnt(4)" ::: "memory");
    } else {
      asm volatile("s_waitcnt vmcnt(0)" ::: "memory");
    }
    __builtin_amdgcn_s_barrier();

    bf16x8 af[4], bfr[4];
    #pragma unroll
    for (int m = 0; m < 4; ++m) {
      int row = wr * 64 + m * 16 + l15;
      int c = g ^ ((row >> 1) & 3);
      af[m] = *(const bf16x8*)&As[cur][row * 32 + c * 8];
    }
    #pragma unroll
    for (int n = 0; n < 4; ++n) {
      int row = wc * 64 + n * 16 + l15;
      int c = g ^ ((row >> 1) & 3);
      bfr[n] = *(const bf16x8*)&Bs[cur][row * 32 + c * 8];
    }
    #pragma unroll
    for (int m = 0; m < 4; ++m)
      #pragma unroll
      for (int n = 0; n < 4; ++n)
        acc[m][n] = MFMA16(af[m], bfr[n], acc[m][n]);

    __builtin_amdgcn_s_barrier();
  }

  #pragma unroll
  for (int m = 0; m < 4; ++m)
    #pragma unroll
    for (int n = 0; n < 4; ++n) {
      int col = bn + wc * 64 + n * 16 + l15;
      float bv = bias[col];
      #pragma unroll
      for (int r = 0; r < 4; ++r) {
        int row = bm + wr * 64 + m * 16 + g * 4 + r;
        float v = acc[m][n][r] + bv;
        if (OUT_F32) ((float*)Cout)[(size_t)row * N + col] = v;
        else         ((ushort*)Cout)[(size_t)row * N + col] = f2bf(v);
      }
    }
}

// ---------------------------------------------------------------------------
// Attention (MFMA). Block = (b,h), 256 threads = 4 waves, wave w owns queries
// q0 = w*64 .. +63. K staged swizzled via global_load_lds; V staged transposed
// [d][key] (pad 392 -> conflict-free b128 reads). Per 32-key chunk: QK^T MFMA,
// mask+exp (plain exp, logits tiny), P -> per-wave swizzled LDS tile, PV MFMA.
// Only memory chunks + the causal-local band chunks are visited.
// ---------------------------------------------------------------------------
__global__ __launch_bounds__(256, 1)
void k_attn(const ushort* __restrict__ qkv, const ushort* __restrict__ mem_bf,
            const float* __restrict__ gate, ushort* __restrict__ y)
{
  __shared__ ushort Ks[TT_ * 64];        // [row][64], chunk-swizzled (c ^= row&7)
  __shared__ ushort Vt[64 * 392];        // [d][key], ld=392
  __shared__ ushort Pb[4][64 * 32];      // per-wave P tile, sigma-swizzled

  const int b = blockIdx.x, h = blockIdx.y;
  const int tid = threadIdx.x, lane = tid & 63, w = tid >> 6;
  const int g = lane >> 4, l15 = lane & 15;
  const int q0 = w * 64;

  const ushort* qkv_b  = qkv + (size_t)b * T_ * C3_ + h * 64;  // row stride C3_
  const ushort* memb_h = mem_bf + h * 64;                      // row stride C_

  // ---- stage Ks: 3072 16B slots ----
  #pragma unroll
  for (int i = 0; i < 12; ++i) {
    int s = i * 256 + tid;
    int row = s >> 3, cS = s & 7;
    int c = cS ^ (row & 7);
    const ushort* src = (row < M_)
        ? memb_h + (size_t)row * C_ + c * 8
        : qkv_b + (size_t)(row - M_) * C3_ + C_ + c * 8;
    gload_lds16(src, &Ks[s * 8]);
  }

  // ---- stage Vt (transposed, u32-packed along keys) ----
  for (int it = tid; it < 32 * 192; it += 256) {
    int d2 = it & 31, kp = it >> 5;
    int k0 = kp * 2, k1 = k0 + 1;
    uint a0 = (k0 < M_) ? *(const uint*)&memb_h[(size_t)k0 * C_ + 2 * d2]
                        : *(const uint*)&qkv_b[(size_t)(k0 - M_) * C3_ + 2 * C_ + 2 * d2];
    uint a1 = (k1 < M_) ? *(const uint*)&memb_h[(size_t)k1 * C_ + 2 * d2]
                        : *(const uint*)&qkv_b[(size_t)(k1 - M_) * C3_ + 2 * C_ + 2 * d2];
    uint lo = (a0 & 0xffffu) | (a1 << 16);
    uint hi = (a0 >> 16)     | (a1 & 0xffff0000u);
    *(uint*)&Vt[(2 * d2)     * 392 + 2 * kp] = lo;
    *(uint*)&Vt[(2 * d2 + 1) * 392 + 2 * kp] = hi;
  }

  // ---- Q fragments in registers ----
  bf16x8 qf[4][2];
  #pragma unroll
  for (int m = 0; m < 4; ++m)
    #pragma unroll
    for (int kk = 0; kk < 2; ++kk)
      qf[m][kk] = *(const bf16x8*)&qkv_b[(size_t)(q0 + m * 16 + l15) * C3_ + kk * 32 + g * 8];

  __syncthreads();   // drains vmcnt (global_load_lds) + lds writes

  f32x4 yacc[4][4] = {};
  float rsum[4][4] = {};
  ushort* P = &Pb[w][0];

  const int nch_self = (q0 == 0) ? 2 : 4;
  const int ss = M_ + ((q0 > WIN_) ? (q0 - WIN_) : 0);   // first self band row

  for (int ch = 0; ch < 4 + nch_self; ++ch) {
    const int r0 = (ch < 4) ? ch * 32 : ss + (ch - 4) * 32;

    // ---- QK^T: S[64 q][32 keys] in frags ----
    f32x4 s_[4][2];
    #pragma unroll
    for (int m = 0; m < 4; ++m)
      #pragma unroll
      for (int n = 0; n < 2; ++n)
        s_[m][n] = (f32x4){0.f, 0.f, 0.f, 0.f};
    #pragma unroll
    for (int n = 0; n < 2; ++n) {
      #pragma unroll
      for (int kk = 0; kk < 2; ++kk) {
        int row = r0 + n * 16 + l15;
        int c = (kk * 4 + g) ^ (row & 7);
        bf16x8 kf = *(const bf16x8*)&Ks[row * 64 + c * 8];
        #pragma unroll
        for (int m = 0; m < 4; ++m)
          s_[m][n] = MFMA16(qf[m][kk], kf, s_[m][n]);
      }
    }

    // ---- mask + exp + write P (per-wave buffer, no barrier needed) ----
    #pragma unroll
    for (int m = 0; m < 4; ++m)
      #pragma unroll
      for (int n = 0; n < 2; ++n) {
        int key_row = r0 + n * 16 + l15;
        int j = key_row - M_;
        int kc = n * 16 + l15;
        #pragma unroll
        for (int r = 0; r < 4; ++r) {
          int qi = q0 + m * 16 + g * 4 + r;
          bool ok = (key_row < M_) || ((j <= qi) && (qi - j <= WIN_));
          float p = ok ? __expf(s_[m][n][r] * 0.125f) : 0.f;
          rsum[m][r] += p;
          int ql = m * 16 + g * 4 + r;
          int sig = ((ql >> 1) ^ (ql >> 2)) & 3;
          P[ql * 32 + (kc ^ (sig << 3))] = f2bf(p);
        }
      }

    // ---- PV: yacc += P[64x32] * V[32 keys x 64 d] ----
    bf16x8 pa[4];
    #pragma unroll
    for (int m = 0; m < 4; ++m) {
      int row = m * 16 + l15;
      int sig = ((row >> 1) ^ (row >> 2)) & 3;
      pa[m] = *(const bf16x8*)&P[row * 32 + ((g ^ sig) << 3)];
    }
    #pragma unroll
    for (int n = 0; n < 4; ++n) {
      int dd = n * 16 + l15;
      bf16x8 vb = *(const bf16x8*)&Vt[dd * 392 + r0 + g * 8];
      #pragma unroll
      for (int m = 0; m < 4; ++m)
        yacc[m][n] = MFMA16(pa[m], vb, yacc[m][n]);
    }
  }

  // ---- row-sum reduce across the 16 lanes sharing each row ----
  float inv[4][4];
  #pragma unroll
  for (int m = 0; m < 4; ++m)
    #pragma unroll
    for (int r = 0; r < 4; ++r) {
      float v = rsum[m][r];
      v += __shfl_xor(v, 1); v += __shfl_xor(v, 2);
      v += __shfl_xor(v, 4); v += __shfl_xor(v, 8);
      inv[m][r] = 1.f / v;
    }

  // ---- epilogue: y = (P V / l) * gate, bf16 ----
  #pragma unroll
  for (int m = 0; m < 4; ++m)
    #pragma unroll
    for (int n = 0; n < 4; ++n) {
      int dd = n * 16 + l15;
      float gv = gate[h * 64 + dd];
      #pragma unroll
      for (int r = 0; r < 4; ++r) {
        int qi = q0 + m * 16 + g * 4 + r;
        y[(size_t)(b * T_ + qi) * C_ + h * 64 + dd] = f2bf(yacc[m][n][r] * inv[m][r] * gv);
      }
    }
}

// ---------------------------------------------------------------------------
extern "C" void kernel_launch(void* const* d_in, const int* in_sizes, int n_in,
                              void* d_out, int out_size, void* d_ws, size_t ws_size,
                              hipStream_t stream) {
  const float* x      = (const float*)d_in[0];
  const float* memory = (const float*)d_in[1];
  const float* W_qkv  = (const float*)d_in[2];
  const float* b_qkv  = (const float*)d_in[3];
  const float* W_proj = (const float*)d_in[4];
  const float* b_proj = (const float*)d_in[5];
  const float* gate   = (const float*)d_in[6];
  float* out = (float*)d_out;

  // workspace layout (ushort units), total ~97.2 MiB
  ushort* Wq_t  = (ushort*)d_ws;                       //  442368
  ushort* Wp_t  = Wq_t + (size_t)C_ * C3_;             //  147456
  ushort* membf = Wp_t + (size_t)C_ * C_;              //   49152
  ushort* qkvw  = membf + (size_t)M_ * C_;             // 37748736
  ushort* xybf  = qkvw + (size_t)B_ * T_ * C3_;        // 12582912 (x_bf, then y)

  dim3 blk(256);

  int prep_items = NX4_ + NM4_ + NWQ_ + NWP_;
  k_prep<<<dim3((prep_items + 255) / 256), blk, 0, stream>>>(
      x, memory, W_qkv, W_proj, xybf, membf, Wq_t, Wp_t);

  k_gemm<C3_, false><<<dim3(B_ * T_ / 128, C3_ / 128), blk, 0, stream>>>(
      xybf, Wq_t, b_qkv, qkvw);

  k_attn<<<dim3(B_, H_), blk, 0, stream>>>(qkvw, membf, gate, xybf);

  k_gemm<C_, true><<<dim3(B_ * T_ / 128, C_ / 128), blk, 0, stream>>>(
      xybf, Wp_t, b_proj, out);
}

// Round 5
// 129.803 us; speedup vs baseline: 8.1900x; 1.2616x over previous
//
#include <hip/hip_runtime.h>

#define B_   128
#define T_   256
#define C_   384
#define H_   6
#define D_   64
#define M_   128
#define WIN_ 64
#define C3_  1152
#define QKS_ 768   // qk workspace row stride (q cols 0..383, k cols 384..767)

typedef unsigned int   uint;
typedef unsigned short ushort;
typedef __attribute__((ext_vector_type(8))) short bf16x8;
typedef __attribute__((ext_vector_type(4))) float f32x4;

#define AS1 __attribute__((address_space(1)))
#define AS3 __attribute__((address_space(3)))
#define MFMA16(a,b,c) __builtin_amdgcn_mfma_f32_16x16x32_bf16((a),(b),(c),0,0,0)

__device__ __forceinline__ ushort f2bf(float f) {
  union { float f; uint u; } c; c.f = f;
  uint x = c.u;
  return (ushort)((x + 0x7fffu + ((x >> 16) & 1u)) >> 16);  // RNE
}
__device__ __forceinline__ void gload_lds16(const ushort* g, ushort* l) {
  __builtin_amdgcn_global_load_lds((const AS1 uint*)g, (AS3 uint*)l, 16, 0, 0);
}

// ---------------------------------------------------------------------------
// Prep (segmented, all patterns from the validated round-2 kernel + memT):
// x->bf16, memory->bf16, memT[h][d][k], Wq_t[n][k], Wp_t[n][k].
// ---------------------------------------------------------------------------
#define NX4_  ((B_ * T_ * C_) / 4)   // 3145728
#define NM4_  ((M_ * C_) / 4)        // 12288
#define NMT_  (H_ * 64 * 128)        // 49152
#define NWQ_  (C_ * C3_)             // 442368
#define NWP_  (C_ * C_)              // 147456

__global__ __launch_bounds__(256)
void k_prep(const float* __restrict__ x, const float* __restrict__ memory,
            const float* __restrict__ Wq, const float* __restrict__ Wp,
            ushort* __restrict__ x_bf, ushort* __restrict__ mem_bf,
            ushort* __restrict__ memT, ushort* __restrict__ Wq_t,
            ushort* __restrict__ Wp_t)
{
  int id = blockIdx.x * 256 + threadIdx.x;
  if (id < NX4_) {
    float4 f = ((const float4*)x)[id];
    ushort4 u; u.x = f2bf(f.x); u.y = f2bf(f.y); u.z = f2bf(f.z); u.w = f2bf(f.w);
    *(ushort4*)&x_bf[id * 4] = u;
    return;
  }
  id -= NX4_;
  if (id < NM4_) {
    float4 f = ((const float4*)memory)[id];
    ushort4 u; u.x = f2bf(f.x); u.y = f2bf(f.y); u.z = f2bf(f.z); u.w = f2bf(f.w);
    *(ushort4*)&mem_bf[id * 4] = u;
    return;
  }
  id -= NM4_;
  if (id < NMT_) {                 // memT[(h*64+d)*128 + k] = memory[k][h*64+d]
    int k = id & 127;
    int hd = id >> 7;
    int h = hd >> 6, d = hd & 63;
    memT[id] = f2bf(memory[(size_t)k * C_ + h * 64 + d]);
    return;
  }
  id -= NMT_;
  if (id < NWQ_) {                 // Wq_t[n*384 + k] = Wq[k*1152 + n]
    int n = id / C_, k = id % C_;
    Wq_t[id] = f2bf(Wq[(size_t)k * C3_ + n]);
    return;
  }
  id -= NWQ_;
  if (id < NWP_) {                 // Wp_t[n*384 + k] = Wp[k*384 + n]
    int n = id / C_, k = id % C_;
    Wp_t[id] = f2bf(Wp[(size_t)k * C_ + n]);
  }
}

// ---------------------------------------------------------------------------
// MFMA GEMM (validated core), 128x128 tile, BK=32, XCD-bijective mapping.
// MODE 0 (qkv): cols 0..767 -> scalar bf16 store to qkw (stride 768, validated
//   pattern); cols 768..1151 (v) -> transposed store vT[b][h][d][key].
// MODE 1 (proj): direct f32 stores (validated pattern).
// ---------------------------------------------------------------------------
template<int MODE>
__global__ __launch_bounds__(256, 2)
void k_gemm(const ushort* __restrict__ A, const ushort* __restrict__ Bt,
            const float* __restrict__ bias, ushort* __restrict__ qkw,
            ushort* __restrict__ vTw, float* __restrict__ outf)
{
  __shared__ __align__(16) ushort smem[16384];
  constexpr int NT = MODE ? 3 : 9;
  const int wg = blockIdx.x;
  const int X = wg & 7, j = wg >> 3;
  const int bmT = X * 32 + j / NT;
  const int by = j - (j / NT) * NT;
  const int bm = bmT * 128, bn = by * 128;
  const int tid = threadIdx.x;
  const int lane = tid & 63, w = tid >> 6;
  const int wr = w >> 1, wc = w & 1;
  const int g = lane >> 4, l15 = lane & 15;

  f32x4 acc[4][4] = {};

  auto stage = [&](int buf, int k0) {
    #pragma unroll
    for (int i = 0; i < 2; ++i) {
      int s = i * 256 + tid;
      int row = s >> 2, cS = s & 3;
      int c = cS ^ ((row >> 1) & 3);
      gload_lds16(A  + (size_t)(bm + row) * C_ + k0 + c * 8, &smem[buf * 4096 + s * 8]);
      gload_lds16(Bt + (size_t)(bn + row) * C_ + k0 + c * 8, &smem[8192 + buf * 4096 + s * 8]);
    }
  };

  stage(0, 0);
  for (int t = 0; t < 12; ++t) {
    int cur = t & 1;
    if (t < 11) {
      stage(cur ^ 1, (t + 1) * 32);
      asm volatile("s_waitcnt vmcnt(4)" ::: "memory");
    } else {
      asm volatile("s_waitcnt vmcnt(0)" ::: "memory");
    }
    __builtin_amdgcn_s_barrier();

    bf16x8 af[4], bfr[4];
    #pragma unroll
    for (int m = 0; m < 4; ++m) {
      int row = wr * 64 + m * 16 + l15;
      int c = g ^ ((row >> 1) & 3);
      af[m] = *(const bf16x8*)&smem[cur * 4096 + row * 32 + c * 8];
    }
    #pragma unroll
    for (int n = 0; n < 4; ++n) {
      int row = wc * 64 + n * 16 + l15;
      int c = g ^ ((row >> 1) & 3);
      bfr[n] = *(const bf16x8*)&smem[8192 + cur * 4096 + row * 32 + c * 8];
    }
    #pragma unroll
    for (int m = 0; m < 4; ++m)
      #pragma unroll
      for (int n = 0; n < 4; ++n)
        acc[m][n] = MFMA16(af[m], bfr[n], acc[m][n]);

    __builtin_amdgcn_s_barrier();
  }

  if (MODE == 1) {
    #pragma unroll
    for (int m = 0; m < 4; ++m)
      #pragma unroll
      for (int n = 0; n < 4; ++n) {
        int col = bn + wc * 64 + n * 16 + l15;
        float bv = bias[col];
        #pragma unroll
        for (int r = 0; r < 4; ++r) {
          int row = bm + wr * 64 + m * 16 + g * 4 + r;
          outf[(size_t)row * C_ + col] = acc[m][n][r] + bv;
        }
      }
  } else if (by < 6) {
    // q,k columns: validated scalar bf16 store (stride 768)
    #pragma unroll
    for (int m = 0; m < 4; ++m)
      #pragma unroll
      for (int n = 0; n < 4; ++n) {
        int col = bn + wc * 64 + n * 16 + l15;
        float bv = bias[col];
        #pragma unroll
        for (int r = 0; r < 4; ++r) {
          int row = bm + wr * 64 + m * 16 + g * 4 + r;
          qkw[(size_t)row * QKS_ + col] = f2bf(acc[m][n][r] + bv);
        }
      }
  } else {
    // v columns: transposed store vT[((b*6+h)*64+d)*256 + key], 4 keys packed
    #pragma unroll
    for (int m = 0; m < 4; ++m)
      #pragma unroll
      for (int n = 0; n < 4; ++n) {
        int col = bn + wc * 64 + n * 16 + l15;
        int ch = col - 768, hh = ch >> 6, dd = ch & 63;
        float bv = bias[col];
        int row0 = bm + wr * 64 + m * 16 + g * 4;
        int bb = row0 >> 8, key0 = row0 & 255;
        uint lo = (uint)f2bf(acc[m][n][0] + bv) | ((uint)f2bf(acc[m][n][1] + bv) << 16);
        uint hi = (uint)f2bf(acc[m][n][2] + bv) | ((uint)f2bf(acc[m][n][3] + bv) << 16);
        uint2 uu; uu.x = lo; uu.y = hi;
        *(uint2*)(vTw + ((size_t)(bb * H_ + hh) * 64 + dd) * 256 + key0) = uu;
      }
  }
}

// ---------------------------------------------------------------------------
// Attention — round-2 validated dataflow (Q-as-A, K-as-B, P via sig-swizzled
// LDS, V-as-B), with two isolated changes:
//   (1) Ks layout [2][384][32]: 64B rows + (row>>1)&3 XOR (the k_gemm pattern)
//       -> kills the 8-way bank conflicts of the old 128B rows.
//   (2) V fragments read directly from global vTw/memT (L2-hot) -> drops the
//       50KB Vt LDS + its staging VALU; LDS 113KB -> 64KB -> 2 blocks/CU.
// ---------------------------------------------------------------------------
__global__ __launch_bounds__(256, 2)
void k_attn(const ushort* __restrict__ qkw, const ushort* __restrict__ vTw,
            const ushort* __restrict__ membf, const ushort* __restrict__ memT,
            const float* __restrict__ gate, ushort* __restrict__ y)
{
  __shared__ ushort Ks[2][384][32];   // [kk-half][key_row][32], col-XOR swizzled
  __shared__ ushort Pb[4][64 * 32];   // per-wave P tile, sigma-swizzled

  const int b = blockIdx.x, h = blockIdx.y;
  const int tid = threadIdx.x, lane = tid & 63, w = tid >> 6;
  const int g = lane >> 4, l15 = lane & 15;
  const int q0 = w * 64;

  const ushort* qbase = qkw + (size_t)b * T_ * QKS_ + h * 64;
  const ushort* kcols = qbase + C_;                       // k columns
  const ushort* vbase = vTw + (size_t)(b * H_ + h) * 64 * 256;
  const ushort* mTb   = memT + (size_t)h * 64 * 128;

  // ---- stage Ks: 3072 16B slots; rows 0..127 = memory, 128..383 = self k ----
  #pragma unroll
  for (int i = 0; i < 12; ++i) {
    int s = i * 256 + tid;
    int kk = s / 1536, r4 = s - kk * 1536;
    int row = r4 >> 2, c8 = r4 & 3;
    int c = c8 ^ ((row >> 1) & 3);                        // inverse swizzle on source
    const ushort* src = (row < M_)
        ? membf + (size_t)row * C_ + h * 64 + kk * 32 + c * 8
        : kcols + (size_t)(row - M_) * QKS_ + kk * 32 + c * 8;
    gload_lds16(src, &Ks[0][0][0] + s * 8);
  }

  // ---- Q fragments (validated pattern) ----
  bf16x8 qf[4][2];
  #pragma unroll
  for (int m = 0; m < 4; ++m)
    #pragma unroll
    for (int kk = 0; kk < 2; ++kk)
      qf[m][kk] = *(const bf16x8*)(qbase + (size_t)(q0 + m * 16 + l15) * QKS_ + kk * 32 + g * 8);

  __syncthreads();   // drains global_load_lds

  f32x4 yacc[4][4] = {};
  float rsum[4][4] = {};
  ushort* P = &Pb[w][0];

  const int nch_self = (q0 == 0) ? 2 : 4;
  const int ss = M_ + ((q0 > WIN_) ? (q0 - WIN_) : 0);    // first self band row

  for (int ch = 0; ch < 4 + nch_self; ++ch) {
    const int r0 = (ch < 4) ? ch * 32 : ss + (ch - 4) * 32;
    const bool is_mem = (ch < 4);
    const ushort* vsrc = is_mem ? mTb : vbase;
    const int vld = is_mem ? 128 : 256;
    const int keyoff = is_mem ? r0 : (r0 - M_);

    // ---- QK^T: S[64 q][32 keys] (Q as A, K as B — validated orientation) ----
    f32x4 s_[4][2];
    #pragma unroll
    for (int m = 0; m < 4; ++m)
      #pragma unroll
      for (int n = 0; n < 2; ++n)
        s_[m][n] = (f32x4){0.f, 0.f, 0.f, 0.f};
    #pragma unroll
    for (int n = 0; n < 2; ++n) {
      int R = r0 + n * 16 + l15;
      int c = g ^ ((R >> 1) & 3);
      #pragma unroll
      for (int kk = 0; kk < 2; ++kk) {
        bf16x8 kf = *(const bf16x8*)&Ks[kk][R][c * 8];
        #pragma unroll
        for (int m = 0; m < 4; ++m)
          s_[m][n] = MFMA16(qf[m][kk], kf, s_[m][n]);
      }
    }

    // ---- mask + exp + P write (validated round-2 code) ----
    #pragma unroll
    for (int m = 0; m < 4; ++m)
      #pragma unroll
      for (int n = 0; n < 2; ++n) {
        int key_row = r0 + n * 16 + l15;
        int jj = key_row - M_;
        int kc = n * 16 + l15;
        #pragma unroll
        for (int r = 0; r < 4; ++r) {
          int qi = q0 + m * 16 + g * 4 + r;
          bool ok = (key_row < M_) || ((jj <= qi) && (qi - jj <= WIN_));
          float p = ok ? __expf(s_[m][n][r] * 0.125f) : 0.f;
          rsum[m][r] += p;
          int ql = m * 16 + g * 4 + r;
          int sig = ((ql >> 1) ^ (ql >> 2)) & 3;
          P[ql * 32 + (kc ^ (sig << 3))] = f2bf(p);
        }
      }

    // ---- PV: yacc += P[64x32] * V[32 keys x 64 d], V from global ----
    bf16x8 pa[4];
    #pragma unroll
    for (int m = 0; m < 4; ++m) {
      int row = m * 16 + l15;
      int sig = ((row >> 1) ^ (row >> 2)) & 3;
      pa[m] = *(const bf16x8*)&P[row * 32 + ((g ^ sig) << 3)];
    }
    #pragma unroll
    for (int n = 0; n < 4; ++n) {
      int dd = n * 16 + l15;
      bf16x8 vb = *(const bf16x8*)(vsrc + (size_t)dd * vld + keyoff + g * 8);
      #pragma unroll
      for (int m = 0; m < 4; ++m)
        yacc[m][n] = MFMA16(pa[m], vb, yacc[m][n]);
    }
  }

  // ---- row-sum reduce across the 16 lanes sharing each q row ----
  float inv[4][4];
  #pragma unroll
  for (int m = 0; m < 4; ++m)
    #pragma unroll
    for (int r = 0; r < 4; ++r) {
      float v = rsum[m][r];
      v += __shfl_xor(v, 1); v += __shfl_xor(v, 2);
      v += __shfl_xor(v, 4); v += __shfl_xor(v, 8);
      inv[m][r] = 1.f / v;
    }

  // ---- epilogue: y = (P V / l) * gate, bf16 (validated round-2 write) ----
  #pragma unroll
  for (int m = 0; m < 4; ++m)
    #pragma unroll
    for (int n = 0; n < 4; ++n) {
      int dd = n * 16 + l15;
      float gv = gate[h * 64 + dd];
      #pragma unroll
      for (int r = 0; r < 4; ++r) {
        int qi = q0 + m * 16 + g * 4 + r;
        y[(size_t)(b * T_ + qi) * C_ + h * 64 + dd] = f2bf(yacc[m][n][r] * inv[m][r] * gv);
      }
    }
}

// ---------------------------------------------------------------------------
extern "C" void kernel_launch(void* const* d_in, const int* in_sizes, int n_in,
                              void* d_out, int out_size, void* d_ws, size_t ws_size,
                              hipStream_t stream) {
  const float* x      = (const float*)d_in[0];
  const float* memory = (const float*)d_in[1];
  const float* W_qkv  = (const float*)d_in[2];
  const float* b_qkv  = (const float*)d_in[3];
  const float* W_proj = (const float*)d_in[4];
  const float* b_proj = (const float*)d_in[5];
  const float* gate   = (const float*)d_in[6];
  float* out = (float*)d_out;

  ushort* p = (ushort*)d_ws;
  ushort* Wq_t  = p;  p += (size_t)C_ * C3_;          //   442368
  ushort* Wp_t  = p;  p += (size_t)C_ * C_;           //   147456
  ushort* membf = p;  p += (size_t)M_ * C_;           //    49152
  ushort* memT  = p;  p += (size_t)NMT_;              //    49152
  ushort* qkw   = p;  p += (size_t)B_ * T_ * QKS_;    // 25165824
  ushort* vTw   = p;  p += (size_t)B_ * T_ * C_;      // 12582912
  ushort* xybf  = p;  p += (size_t)B_ * T_ * C_;      // 12582912 (x_bf, then y)

  dim3 blk(256);

  int prep_items = NX4_ + NM4_ + NMT_ + NWQ_ + NWP_;
  k_prep<<<dim3((prep_items + 255) / 256), blk, 0, stream>>>(
      x, memory, W_qkv, W_proj, xybf, membf, memT, Wq_t, Wp_t);

  k_gemm<0><<<dim3(2304), blk, 0, stream>>>(xybf, Wq_t, b_qkv, qkw, vTw, nullptr);

  k_attn<<<dim3(B_, H_), blk, 0, stream>>>(qkw, vTw, membf, memT, gate, xybf);

  k_gemm<1><<<dim3(768), blk, 0, stream>>>(xybf, Wp_t, b_proj, nullptr, nullptr, out);
}